// Round 4
// baseline (2343.633 us; speedup 1.0000x reference)
//
#include <hip/hip_runtime.h>
#include <stdint.h>
#include <stddef.h>

#define NROWS 8192
#define NCOLS 8192       // K dimension = noise-matrix column count
#define DDIM  1024
#define NCHUNK 64        // 128 rows per chunk
#define GEN_BLOCKS 256
#define GEMM_BLOCKS 512

typedef float  f32x4 __attribute__((ext_vector_type(4)));
typedef _Float16 f16x8 __attribute__((ext_vector_type(8)));

#if __has_builtin(__builtin_amdgcn_exp2f)
#define EXP2F(x) __builtin_amdgcn_exp2f(x)
#else
#define EXP2F(x) exp2f(x)
#endif
#if __has_builtin(__builtin_amdgcn_logf)
#define LOG2F(x) __builtin_amdgcn_logf(x)     // v_log_f32 = log2
#else
#define LOG2F(x) log2f(x)
#endif
#if __has_builtin(__builtin_amdgcn_sqrtf)
#define SQRTF(x) __builtin_amdgcn_sqrtf(x)
#else
#define SQRTF(x) sqrtf(x)
#endif

// ---------------- Threefry-2x32, key = (0, 42) (jax.random.key(42)) ---------
__device__ __forceinline__ uint32_t rotl32(uint32_t x, uint32_t r){
  return (x << r) | (x >> (32u - r));
}

__device__ __forceinline__ void threefry2x32(uint32_t x0, uint32_t x1,
                                             uint32_t& o0, uint32_t& o1){
  const uint32_t k0 = 0u, k1 = 42u;
  const uint32_t k2 = k0 ^ k1 ^ 0x1BD11BDAu;
  x0 += k0; x1 += k1;
#define TF_R(r) { x0 += x1; x1 = rotl32(x1, r); x1 ^= x0; }
  TF_R(13) TF_R(15) TF_R(26) TF_R(6)
  x0 += k1; x1 += k2 + 1u;
  TF_R(17) TF_R(29) TF_R(16) TF_R(24)
  x0 += k2; x1 += k0 + 2u;
  TF_R(13) TF_R(15) TF_R(26) TF_R(6)
  x0 += k0; x1 += k1 + 3u;
  TF_R(17) TF_R(29) TF_R(16) TF_R(24)
  x0 += k1; x1 += k2 + 4u;
  TF_R(13) TF_R(15) TF_R(26) TF_R(6)
  x0 += k2; x1 += k0 + 5u;
#undef TF_R
  o0 = x0; o1 = x1;
}

// Partitionable-threefry element: flat index f -> E' = exp(2*normal)*2^-4.
__device__ __forceinline__ float elemE(uint32_t f){
  uint32_t o0, o1;
  threefry2x32(0u, f, o0, o1);
  const uint32_t b = o0 ^ o1;
  float u = __uint_as_float((b >> 9) | 0x3F800000u) - 1.0f;   // [0,1)
  const float lo = -0.99999994f;                              // nextafter(-1,0)
  float v = fmaf(u, 2.0f, lo);
  v = fmaxf(v, lo);
  const float t1 = fmaf(-v, v, 1.0f);                         // 1 - v^2
  float w = LOG2F(t1) * (-0.69314718f);                       // -ln(1-v^2)
  float p;
  if (w < 5.0f){
    w -= 2.5f;
    p =              3.97426473e-08f;
    p = fmaf(p, w,   4.85465e-07f);
    p = fmaf(p, w,  -4.98283e-06f);
    p = fmaf(p, w,  -6.21053e-06f);
    p = fmaf(p, w,   3.09120e-04f);
    p = fmaf(p, w,  -1.77290e-03f);
    p = fmaf(p, w,  -5.90817e-03f);
    p = fmaf(p, w,   3.48803163e-01f);
    p = fmaf(p, w,   2.12331355e+00f);
  } else {
    w = SQRTF(w) - 3.0f;
    p =             -2.83147363e-04f;
    p = fmaf(p, w,   1.42765560e-04f);
    p = fmaf(p, w,   1.90825981e-03f);
    p = fmaf(p, w,  -5.19500608e-03f);
    p = fmaf(p, w,   8.11688602e-03f);
    p = fmaf(p, w,  -1.07798386e-02f);
    p = fmaf(p, w,   1.33487061e-02f);
    p = fmaf(p, w,   1.41658096e+00f);
    p = fmaf(p, w,   4.00643396e+00f);
  }
  const float m = p * v;                         // sqrt(2)*erfinv(v) ~ N(0,1)
  return EXP2F(fmaf(m, 2.8853900817779268f, -4.0f)); // exp(2m)*2^-4
}

__device__ __forceinline__ uint32_t pack2h(float a, float b){
  union { _Float16 h[2]; uint32_t u; } pk;
  pk.h[0] = (_Float16)a; pk.h[1] = (_Float16)b;
  return pk.u;
}

__device__ __forceinline__ uint16_t f2h(float a){
  union { _Float16 h; uint16_t u; } c; c.h = (_Float16)a; return c.u;
}

// ---------------- x [8192][1024] f32 -> xT [1024][8192] f16 -----------------
__global__ __launch_bounds__(256) void transpose_cast(const float* __restrict__ x,
                                                      uint16_t* __restrict__ xT){
  __shared__ float tile[32][33];
  const int tx = threadIdx.x & 31;
  const int ty = threadIdx.x >> 5;          // 0..7
  const int dcol = blockIdx.x * 32;
  const int nrow = blockIdx.y * 32;
  #pragma unroll
  for (int r = 0; r < 32; r += 8)
    tile[ty + r][tx] = x[(size_t)(nrow + ty + r) * DDIM + dcol + tx];
  __syncthreads();
  #pragma unroll
  for (int r = 0; r < 32; r += 8)
    xT[(size_t)(dcol + ty + r) * NROWS + nrow + tx] = f2h(tile[tx][ty + r]);
}

// ---------------- GEMM bits shared by fused + fallback ----------------------
#define BM 128
#define BN 128
#define BK 32

typedef const __attribute__((address_space(1))) void GAS;
typedef __attribute__((address_space(3))) void LAS;

__device__ __forceinline__ void gload16(const void* g, void* l){
  __builtin_amdgcn_global_load_lds((GAS*)g, (LAS*)l, 16, 0, 0);
}

// ================== FUSED producer-consumer kernel ==========================
// grid = 768 blocks, 3 blocks/CU co-resident (deadlock-free: producers never
// wait; consumers spin on ready counters while parked at barriers).
// blocks [0,256)   : producers — generate P rows chunk-by-chunk, publish
//                    cnt[2c+h] (h = column half) with agent-release.
// blocks [256,768) : consumers — tile (chunk = (b-256)>>3, ntile = (b-256)&7),
//                    K-loop split at 4096 so MFMA starts on the first half.
__global__ __launch_bounds__(256, 3) void fused_gen_gemm(
    uint16_t* __restrict__ P,           // [8192][8192] f16 (unnormalized E')
    const uint16_t* __restrict__ xT,    // [1024][8192] f16
    float* __restrict__ S,              // [8192] row sums (pre-zeroed)
    uint32_t* __restrict__ cnt,         // [128] ready counters (pre-zeroed)
    float* __restrict__ O)              // [8192][1024] f32
{
  __shared__ uint16_t smem[8192];       // gemm: As[128][32] | Bs[128][32]
  __shared__ float sm[4];               // gen: reduction scratch
  const int b = blockIdx.x;
  const int t = threadIdx.x;

  if (b < GEN_BLOCKS){
    // ------------------------------ producer ------------------------------
    const int rsub = b >> 1;            // row within chunk (0..127)
    const int q = b & 1;                // col-quarter within each half
    for (int c = 0; c < NCHUNK; ++c){
      const int row = c * 128 + rsub;
      const uint32_t base = (uint32_t)row * 8192u;
      uint16_t* __restrict__ prow = P + (size_t)row * NCOLS;
      float part = 0.f;
      #pragma unroll
      for (int h = 0; h < 2; ++h){
        const uint32_t cb = (uint32_t)(h * 4096 + q * 2048);
        #pragma unroll
        for (int s = 0; s < 4; ++s){
          const uint32_t j0 = cb + ((uint32_t)s << 9) + ((uint32_t)t << 1);
          const float e0 = elemE(base + j0);
          const float e1 = elemE(base + j0 + 1u);
          part += e0 + e1;
          *reinterpret_cast<uint32_t*>(prow + j0) = pack2h(e0, e1);
        }
        if (h == 0){
          __syncthreads();              // drains vmcnt: half-0 stores in L2
          if (t == 0){
            __threadfence();
            __hip_atomic_fetch_add(&cnt[2*c], 1u, __ATOMIC_RELEASE,
                                   __HIP_MEMORY_SCOPE_AGENT);
          }
        }
      }
      // block-reduce part -> atomicAdd S[row], then publish half 1
      float v = part;
      #pragma unroll
      for (int off = 32; off > 0; off >>= 1) v += __shfl_down(v, off, 64);
      if ((t & 63) == 0) sm[t >> 6] = v;
      __syncthreads();                  // drains vmcnt: half-1 stores in L2
      if (t == 0){
        atomicAdd(&S[row], (sm[0] + sm[1]) + (sm[2] + sm[3]));
        __threadfence();
        __hip_atomic_fetch_add(&cnt[2*c + 1], 1u, __ATOMIC_RELEASE,
                               __HIP_MEMORY_SCOPE_AGENT);
      }
    }
  } else {
    // ------------------------------ consumer ------------------------------
    const int tile = b - GEN_BLOCKS;    // 0..511
    const int cidx = tile >> 3;         // chunk / mtile 0..63
    const size_t m0 = (size_t)cidx * BM;
    const size_t n0 = (size_t)(tile & 7) * BN;

    uint16_t* As = smem;
    uint16_t* Bs = smem + 4096;
    const int lane = t & 63;
    const int wave = t >> 6;
    const int wr = (wave >> 1) * 64;
    const int wc = (wave & 1) * 64;
    const int l15 = lane & 15;
    const int lq  = lane >> 4;

    const int lin0 = t, lin1 = t + 256;
    const int r0s = lin0 >> 2, k0s = (lin0 & 3) << 3;
    const int r1s = lin1 >> 2, k1s = (lin1 & 3) << 3;

    const uint16_t* gA0 = P  + (m0 + r0s) * (size_t)NCOLS + k0s;
    const uint16_t* gA1 = P  + (m0 + r1s) * (size_t)NCOLS + k1s;
    const uint16_t* gB0 = xT + (n0 + r0s) * (size_t)NCOLS + k0s;
    const uint16_t* gB1 = xT + (n0 + r1s) * (size_t)NCOLS + k1s;

    f32x4 acc[4][4];
    #pragma unroll
    for (int i = 0; i < 4; ++i)
      #pragma unroll
      for (int j = 0; j < 4; ++j)
        #pragma unroll
        for (int qq = 0; qq < 4; ++qq) acc[i][j][qq] = 0.0f;

    #pragma unroll 1
    for (int half = 0; half < 2; ++half){
      if (t == 0){
        while (__hip_atomic_load(&cnt[2*cidx + half], __ATOMIC_ACQUIRE,
                                 __HIP_MEMORY_SCOPE_AGENT) < (uint32_t)GEN_BLOCKS)
          __builtin_amdgcn_s_sleep(32);
      }
      __syncthreads();
      const int kend = (half + 1) * 4096;
      for (int k0 = half * 4096; k0 < kend; k0 += BK){
        gload16(gA0 + k0, As + lin0 * 8);
        gload16(gA1 + k0, As + lin1 * 8);
        gload16(gB0 + k0, Bs + lin0 * 8);
        gload16(gB1 + k0, Bs + lin1 * 8);
        __syncthreads();
        f16x8 af[4], bfrag[4];
        #pragma unroll
        for (int i = 0; i < 4; ++i)
          af[i] = *reinterpret_cast<const f16x8*>(As + (wr + i*16 + l15) * BK + lq * 8);
        #pragma unroll
        for (int j = 0; j < 4; ++j)
          bfrag[j] = *reinterpret_cast<const f16x8*>(Bs + (wc + j*16 + l15) * BK + lq * 8);
        #pragma unroll
        for (int i = 0; i < 4; ++i)
          #pragma unroll
          for (int j = 0; j < 4; ++j)
            acc[i][j] = __builtin_amdgcn_mfma_f32_16x16x32_f16(af[i], bfrag[j], acc[i][j], 0, 0, 0);
        __syncthreads();
      }
    }

    #pragma unroll
    for (int i = 0; i < 4; ++i){
      float rinv[4];
      #pragma unroll
      for (int r = 0; r < 4; ++r)
        rinv[r] = 1.0f / S[m0 + wr + i*16 + lq*4 + r];
      #pragma unroll
      for (int j = 0; j < 4; ++j){
        const size_t col = n0 + wc + j*16 + l15;
        #pragma unroll
        for (int r = 0; r < 4; ++r){
          const size_t row = m0 + wr + i*16 + lq*4 + r;  // C/D: col=lane&15, row=quad*4+reg
          O[row * DDIM + col] = acc[i][j][r] * rinv[r];
        }
      }
    }
  }
}

// ================== Fallback (small workspace): unfused =====================
__global__ __launch_bounds__(256) void gen_rows(uint16_t* __restrict__ P,
                                                float* __restrict__ S, int row0){
  const int gi = row0 + blockIdx.x;
  const uint32_t base = (uint32_t)gi * 8192u;
  const int t = threadIdx.x;
  uint16_t* __restrict__ prow = P + (size_t)blockIdx.x * NCOLS;
  float acc = 0.0f;
  #pragma unroll 2
  for (int s = 0; s < 16; ++s){
    const uint32_t j0 = ((uint32_t)s << 9) | ((uint32_t)t << 1);
    const float e0 = elemE(base + j0);
    const float e1 = elemE(base + j0 + 1u);
    acc += e0 + e1;
    *reinterpret_cast<uint32_t*>(prow + j0) = pack2h(e0, e1);
  }
  #pragma unroll
  for (int off = 32; off > 0; off >>= 1) acc += __shfl_down(acc, off, 64);
  __shared__ float sm[4];
  if ((t & 63) == 0) sm[t >> 6] = acc;
  __syncthreads();
  if (t == 0) S[gi] = (sm[0] + sm[1]) + (sm[2] + sm[3]);
}

__global__ __launch_bounds__(256, 2) void gemm_rows(
    const uint16_t* __restrict__ P, const uint16_t* __restrict__ xT,
    const float* __restrict__ S, int row0, float* __restrict__ O)
{
  __shared__ uint16_t smem[8192];
  uint16_t* As = smem;
  uint16_t* Bs = smem + 4096;
  const int tid = threadIdx.x;
  const int lane = tid & 63;
  const int wave = tid >> 6;
  const int wr = (wave >> 1) * 64;
  const int wc = (wave & 1) * 64;
  const int l15 = lane & 15;
  const int lq  = lane >> 4;
  const size_t m0 = (size_t)blockIdx.x * BM;
  const size_t n0 = (size_t)blockIdx.y * BN;
  const int lin0 = tid, lin1 = tid + 256;
  const int r0s = lin0 >> 2, k0s = (lin0 & 3) << 3;
  const int r1s = lin1 >> 2, k1s = (lin1 & 3) << 3;
  const uint16_t* gA0 = P  + (m0 + r0s) * (size_t)NCOLS + k0s;
  const uint16_t* gA1 = P  + (m0 + r1s) * (size_t)NCOLS + k1s;
  const uint16_t* gB0 = xT + (n0 + r0s) * (size_t)NCOLS + k0s;
  const uint16_t* gB1 = xT + (n0 + r1s) * (size_t)NCOLS + k1s;
  f32x4 acc[4][4];
  #pragma unroll
  for (int i = 0; i < 4; ++i)
    #pragma unroll
    for (int j = 0; j < 4; ++j)
      #pragma unroll
      for (int q = 0; q < 4; ++q) acc[i][j][q] = 0.0f;
  for (int k0 = 0; k0 < NCOLS; k0 += BK){
    gload16(gA0 + k0, As + lin0 * 8);
    gload16(gA1 + k0, As + lin1 * 8);
    gload16(gB0 + k0, Bs + lin0 * 8);
    gload16(gB1 + k0, Bs + lin1 * 8);
    __syncthreads();
    f16x8 af[4], bfrag[4];
    #pragma unroll
    for (int i = 0; i < 4; ++i)
      af[i] = *reinterpret_cast<const f16x8*>(As + (wr + i*16 + l15) * BK + lq * 8);
    #pragma unroll
    for (int j = 0; j < 4; ++j)
      bfrag[j] = *reinterpret_cast<const f16x8*>(Bs + (wc + j*16 + l15) * BK + lq * 8);
    #pragma unroll
    for (int i = 0; i < 4; ++i)
      #pragma unroll
      for (int j = 0; j < 4; ++j)
        acc[i][j] = __builtin_amdgcn_mfma_f32_16x16x32_f16(af[i], bfrag[j], acc[i][j], 0, 0, 0);
    __syncthreads();
  }
  #pragma unroll
  for (int i = 0; i < 4; ++i){
    float rinv[4];
    #pragma unroll
    for (int r = 0; r < 4; ++r)
      rinv[r] = 1.0f / S[row0 + m0 + wr + i*16 + lq*4 + r];
    #pragma unroll
    for (int j = 0; j < 4; ++j){
      const size_t col = n0 + wc + j*16 + l15;
      #pragma unroll
      for (int r = 0; r < 4; ++r){
        const size_t row = m0 + wr + i*16 + lq*4 + r;
        O[row * DDIM + col] = acc[i][j][r] * rinv[r];
      }
    }
  }
}

// ---------------------------------------------------------------------------
extern "C" void kernel_launch(void* const* d_in, const int* in_sizes, int n_in,
                              void* d_out, int out_size, void* d_ws, size_t ws_size,
                              hipStream_t stream)
{
  (void)in_sizes; (void)n_in; (void)out_size;
  const float* x = (const float*)d_in[0];       // [8192][1024] f32; d_in[1] unused
  float* O = (float*)d_out;                     // [8192][1024] f32
  uint8_t* ws = (uint8_t*)d_ws;

  // layout: cnt[128] u32 | S[8192] f32 | xT (16 MB) | P (134 MB)
  uint32_t* cnt = (uint32_t*)ws;
  const size_t cnt_bytes = 128 * sizeof(uint32_t);
  float* S = (float*)(ws + cnt_bytes);
  const size_t S_bytes = (size_t)NROWS * sizeof(float);
  uint16_t* xT = (uint16_t*)(ws + cnt_bytes + S_bytes);
  const size_t xT_bytes = (size_t)DDIM * NROWS * sizeof(uint16_t);
  uint16_t* P = (uint16_t*)(ws + cnt_bytes + S_bytes + xT_bytes);
  const size_t used = cnt_bytes + S_bytes + xT_bytes;
  const size_t avail = ws_size > used ? ws_size - used : 0;

  hipMemsetAsync(ws, 0, cnt_bytes + S_bytes, stream);   // zero cnt + S
  transpose_cast<<<dim3(DDIM/32, NROWS/32), 256, 0, stream>>>(x, xT);

  const size_t fullP = (size_t)NROWS * NCOLS * sizeof(uint16_t); // 134 MB
  if (avail >= fullP){
    fused_gen_gemm<<<GEN_BLOCKS + GEMM_BLOCKS, 256, 0, stream>>>(P, xT, S, cnt, O);
  } else {
    int R = 128;
    for (int r = 4096; r >= 128; r >>= 1)
      if ((size_t)r * NCOLS * sizeof(uint16_t) <= avail){ R = r; break; }
    for (int r0 = 0; r0 < NROWS; r0 += R){
      gen_rows<<<R, 256, 0, stream>>>(P, S, r0);
      gemm_rows<<<dim3(R/BM, DDIM/BN), 256, 0, stream>>>(P, xT, S, r0, O + (size_t)r0 * DDIM);
    }
  }
}

// Round 5
// 364.425 us; speedup vs baseline: 6.4310x; 6.4310x over previous
//
#include <hip/hip_runtime.h>
#include <stdint.h>
#include <stddef.h>

#define NROWS 8192
#define NCOLS 8192       // K dimension = noise-matrix column count
#define DDIM  1024

typedef float  f32x4 __attribute__((ext_vector_type(4)));
typedef _Float16 f16x8 __attribute__((ext_vector_type(8)));

#if __has_builtin(__builtin_amdgcn_exp2f)
#define EXP2F(x) __builtin_amdgcn_exp2f(x)
#else
#define EXP2F(x) exp2f(x)
#endif
#if __has_builtin(__builtin_amdgcn_logf)
#define LOG2F(x) __builtin_amdgcn_logf(x)     // v_log_f32 = log2
#else
#define LOG2F(x) log2f(x)
#endif
#if __has_builtin(__builtin_amdgcn_sqrtf)
#define SQRTF(x) __builtin_amdgcn_sqrtf(x)
#else
#define SQRTF(x) sqrtf(x)
#endif

// ---------------- Threefry-2x32, key = (0, 42) (jax.random.key(42)) ---------
__device__ __forceinline__ uint32_t rotl32(uint32_t x, uint32_t r){
  return (x << r) | (x >> (32u - r));
}

__device__ __forceinline__ void threefry2x32(uint32_t x0, uint32_t x1,
                                             uint32_t& o0, uint32_t& o1){
  const uint32_t k0 = 0u, k1 = 42u;
  const uint32_t k2 = k0 ^ k1 ^ 0x1BD11BDAu;
  x0 += k0; x1 += k1;
#define TF_R(r) { x0 += x1; x1 = rotl32(x1, r); x1 ^= x0; }
  TF_R(13) TF_R(15) TF_R(26) TF_R(6)
  x0 += k1; x1 += k2 + 1u;
  TF_R(17) TF_R(29) TF_R(16) TF_R(24)
  x0 += k2; x1 += k0 + 2u;
  TF_R(13) TF_R(15) TF_R(26) TF_R(6)
  x0 += k0; x1 += k1 + 3u;
  TF_R(17) TF_R(29) TF_R(16) TF_R(24)
  x0 += k1; x1 += k2 + 4u;
  TF_R(13) TF_R(15) TF_R(26) TF_R(6)
  x0 += k2; x1 += k0 + 5u;
#undef TF_R
  o0 = x0; o1 = x1;
}

// Partitionable-threefry element: flat index f -> E' = exp(2*normal)*2^-4.
// bits = o0^o1 of threefry2x32(key=(0,42), ctr=(0,f));
// normal = sqrt(2)*erfinv(u), u in [nextafter(-1,0),1); sqrt(2) folded into
// the Giles/XLA erfinv polynomial coefficients.
__device__ __forceinline__ float elemE(uint32_t f){
  uint32_t o0, o1;
  threefry2x32(0u, f, o0, o1);
  const uint32_t b = o0 ^ o1;
  float u = __uint_as_float((b >> 9) | 0x3F800000u) - 1.0f;   // [0,1)
  const float lo = -0.99999994f;                              // nextafter(-1,0)
  float v = fmaf(u, 2.0f, lo);
  v = fmaxf(v, lo);
  const float t1 = fmaf(-v, v, 1.0f);                         // 1 - v^2
  float w = LOG2F(t1) * (-0.69314718f);                       // -ln(1-v^2)
  float p;
  if (w < 5.0f){
    w -= 2.5f;
    p =              3.97426473e-08f;
    p = fmaf(p, w,   4.85465e-07f);
    p = fmaf(p, w,  -4.98283e-06f);
    p = fmaf(p, w,  -6.21053e-06f);
    p = fmaf(p, w,   3.09120e-04f);
    p = fmaf(p, w,  -1.77290e-03f);
    p = fmaf(p, w,  -5.90817e-03f);
    p = fmaf(p, w,   3.48803163e-01f);
    p = fmaf(p, w,   2.12331355e+00f);
  } else {
    w = SQRTF(w) - 3.0f;
    p =             -2.83147363e-04f;
    p = fmaf(p, w,   1.42765560e-04f);
    p = fmaf(p, w,   1.90825981e-03f);
    p = fmaf(p, w,  -5.19500608e-03f);
    p = fmaf(p, w,   8.11688602e-03f);
    p = fmaf(p, w,  -1.07798386e-02f);
    p = fmaf(p, w,   1.33487061e-02f);
    p = fmaf(p, w,   1.41658096e+00f);
    p = fmaf(p, w,   4.00643396e+00f);
  }
  const float m = p * v;                         // sqrt(2)*erfinv(v) ~ N(0,1)
  return EXP2F(fmaf(m, 2.8853900817779268f, -4.0f)); // exp(2m)*2^-4
}

__device__ __forceinline__ uint16_t f2h(float a){
  union { _Float16 h; uint16_t u; } c; c.h = (_Float16)a; return c.u;
}

// ---------------- x [8192][1024] f32 -> xT [1024][8192] f16 -----------------
__global__ __launch_bounds__(256) void transpose_cast(const float* __restrict__ x,
                                                      uint16_t* __restrict__ xT){
  __shared__ float tile[32][33];
  const int tx = threadIdx.x & 31;
  const int ty = threadIdx.x >> 5;          // 0..7
  const int dcol = blockIdx.x * 32;
  const int nrow = blockIdx.y * 32;
  #pragma unroll
  for (int r = 0; r < 32; r += 8)
    tile[ty + r][tx] = x[(size_t)(nrow + ty + r) * DDIM + dcol + tx];
  __syncthreads();
  #pragma unroll
  for (int r = 0; r < 32; r += 8)
    xT[(size_t)(dcol + ty + r) * NROWS + nrow + tx] = f2h(tile[tx][ty + r]);
}

// ---------------- generation: E' rows (fp16, unnormalized) + row sums -------
// Block b -> global row row0+b: E'[j] = exp(2*m[gi][j])*2^-4, S[gi] = sum_j E'.
// ILP-8: each thread produces 8 consecutive elements per group and issues one
// 16B global_store_dwordx4 (4 groups of 2048 cols cover the row).
__global__ __launch_bounds__(256) void gen_rows(uint16_t* __restrict__ P,
                                                float* __restrict__ S, int row0){
  const int gi = row0 + blockIdx.x;
  const uint32_t base = (uint32_t)gi * 8192u;
  const int t = threadIdx.x;
  uint16_t* __restrict__ prow = P + (size_t)blockIdx.x * NCOLS;
  float acc = 0.0f;
  #pragma unroll
  for (int g = 0; g < 4; ++g){
    const uint32_t j0 = (uint32_t)(g * 2048) + ((uint32_t)t << 3);
    float e[8];
    #pragma unroll
    for (int i = 0; i < 8; ++i){
      e[i] = elemE(base + j0 + (uint32_t)i);
      acc += e[i];
    }
    f16x8 pk;
    #pragma unroll
    for (int i = 0; i < 8; ++i) pk[i] = (_Float16)e[i];
    *reinterpret_cast<f16x8*>(prow + j0) = pk;    // 16B coalesced store
  }
  // block reduce sum -> S[gi]
  #pragma unroll
  for (int off = 32; off > 0; off >>= 1) acc += __shfl_down(acc, off, 64);
  __shared__ float sm[4];
  if ((t & 63) == 0) sm[t >> 6] = acc;
  __syncthreads();
  if (t == 0) S[gi] = (sm[0] + sm[1]) + (sm[2] + sm[3]);
}

// ---------------- GEMM: O[r][d] = (1/S[r]) * sum_k E'[r][k] * xT[d][k] ------
#define BM 128
#define BN 128
#define BK 32

typedef const __attribute__((address_space(1))) void GAS;
typedef __attribute__((address_space(3))) void LAS;

__device__ __forceinline__ void gload16(const void* g, void* l){
  __builtin_amdgcn_global_load_lds((GAS*)g, (LAS*)l, 16, 0, 0);
}

__global__ __launch_bounds__(256, 2) void gemm_rows(
    const uint16_t* __restrict__ P,     // [Rchunk][8192] f16 (unnormalized E')
    const uint16_t* __restrict__ xT,    // [1024][8192] f16
    const float* __restrict__ S,        // [8192] row sums (global rows)
    int row0,                           // global row of P's row 0
    float* __restrict__ O)              // [Rchunk][1024] f32
{
  __shared__ uint16_t smem[8192];       // As[128][32] | Bs[128][32]
  uint16_t* As = smem;
  uint16_t* Bs = smem + 4096;

  const int tid  = threadIdx.x;
  const int lane = tid & 63;
  const int wave = tid >> 6;
  const int wr = (wave >> 1) * 64;
  const int wc = (wave & 1) * 64;
  const int l15 = lane & 15;
  const int lq  = lane >> 4;

  const size_t m0 = (size_t)blockIdx.x * BM;
  const size_t n0 = (size_t)blockIdx.y * BN;

  const int lin0 = tid, lin1 = tid + 256;
  const int r0s = lin0 >> 2, k0s = (lin0 & 3) << 3;
  const int r1s = lin1 >> 2, k1s = (lin1 & 3) << 3;

  const uint16_t* gA0 = P  + (m0 + r0s) * (size_t)NCOLS + k0s;
  const uint16_t* gA1 = P  + (m0 + r1s) * (size_t)NCOLS + k1s;
  const uint16_t* gB0 = xT + (n0 + r0s) * (size_t)NCOLS + k0s;
  const uint16_t* gB1 = xT + (n0 + r1s) * (size_t)NCOLS + k1s;

  f32x4 acc[4][4];
  #pragma unroll
  for (int i = 0; i < 4; ++i)
    #pragma unroll
    for (int j = 0; j < 4; ++j)
      #pragma unroll
      for (int q = 0; q < 4; ++q) acc[i][j][q] = 0.0f;

  for (int k0 = 0; k0 < NCOLS; k0 += BK){
    gload16(gA0 + k0, As + lin0 * 8);
    gload16(gA1 + k0, As + lin1 * 8);
    gload16(gB0 + k0, Bs + lin0 * 8);
    gload16(gB1 + k0, Bs + lin1 * 8);
    __syncthreads();
    f16x8 af[4], bfrag[4];
    #pragma unroll
    for (int i = 0; i < 4; ++i)
      af[i] = *reinterpret_cast<const f16x8*>(As + (wr + i*16 + l15) * BK + lq * 8);
    #pragma unroll
    for (int j = 0; j < 4; ++j)
      bfrag[j] = *reinterpret_cast<const f16x8*>(Bs + (wc + j*16 + l15) * BK + lq * 8);
    #pragma unroll
    for (int i = 0; i < 4; ++i)
      #pragma unroll
      for (int j = 0; j < 4; ++j)
        acc[i][j] = __builtin_amdgcn_mfma_f32_16x16x32_f16(af[i], bfrag[j], acc[i][j], 0, 0, 0);
    __syncthreads();
  }

  #pragma unroll
  for (int i = 0; i < 4; ++i){
    float rinv[4];
    #pragma unroll
    for (int r = 0; r < 4; ++r)
      rinv[r] = 1.0f / S[row0 + m0 + wr + i*16 + lq*4 + r];
    #pragma unroll
    for (int j = 0; j < 4; ++j){
      const size_t col = n0 + wc + j*16 + l15;
      #pragma unroll
      for (int r = 0; r < 4; ++r){
        const size_t row = m0 + wr + i*16 + lq*4 + r;  // C/D: col=lane&15, row=quad*4+reg
        O[row * DDIM + col] = acc[i][j][r] * rinv[r];
      }
    }
  }
}

// ---------------------------------------------------------------------------
extern "C" void kernel_launch(void* const* d_in, const int* in_sizes, int n_in,
                              void* d_out, int out_size, void* d_ws, size_t ws_size,
                              hipStream_t stream)
{
  (void)in_sizes; (void)n_in; (void)out_size;
  const float* x = (const float*)d_in[0];       // [8192][1024] f32; d_in[1] unused
  float* O = (float*)d_out;                     // [8192][1024] f32
  uint8_t* ws = (uint8_t*)d_ws;

  // layout: S[8192] f32 | xT (16.8 MB) | P (134 MB)
  float* S = (float*)ws;
  const size_t S_bytes = (size_t)NROWS * sizeof(float);
  uint16_t* xT = (uint16_t*)(ws + S_bytes);
  const size_t xT_bytes = (size_t)DDIM * NROWS * sizeof(uint16_t);
  uint16_t* P = (uint16_t*)(ws + S_bytes + xT_bytes);
  const size_t used = S_bytes + xT_bytes;
  const size_t avail = ws_size > used ? ws_size - used : 0;

  transpose_cast<<<dim3(DDIM/32, NROWS/32), 256, 0, stream>>>(x, xT);

  const size_t fullP = (size_t)NROWS * NCOLS * sizeof(uint16_t); // 134 MB
  if (avail >= fullP){
    gen_rows<<<NROWS, 256, 0, stream>>>(P, S, 0);
    gemm_rows<<<dim3(NROWS/BM, DDIM/BN), 256, 0, stream>>>(P, xT, S, 0, O);
  } else {
    int R = 128;
    for (int r = 4096; r >= 128; r >>= 1)
      if ((size_t)r * NCOLS * sizeof(uint16_t) <= avail){ R = r; break; }
    for (int r0 = 0; r0 < NROWS; r0 += R){
      gen_rows<<<R, 256, 0, stream>>>(P, S, r0);
      gemm_rows<<<dim3(R/BM, DDIM/BN), 256, 0, stream>>>(P, xT, S, r0, O + (size_t)r0 * DDIM);
    }
  }
}